// Round 7
// baseline (215.927 us; speedup 1.0000x reference)
//
#include <hip/hip_runtime.h>
#include <hip/hip_bf16.h>

typedef __attribute__((ext_vector_type(8))) unsigned short us8;
typedef __attribute__((ext_vector_type(8))) __bf16 bf16x8;
typedef __attribute__((ext_vector_type(4))) float f32x4;

__device__ __forceinline__ unsigned short f2bf(float f) {
  unsigned int u = __float_as_uint(f);
  u += 0x7FFFu + ((u >> 16) & 1u);   // round-to-nearest-even
  return (unsigned short)(u >> 16);
}
__device__ __forceinline__ float bf2f(unsigned short u) {
  return __uint_as_float(((unsigned int)u) << 16);
}

// direct global->LDS DMA, 16B per lane (dest = wave-uniform base + lane*16)
__device__ __forceinline__ void gld16(const unsigned short* g, unsigned short* l) {
  __builtin_amdgcn_global_load_lds(reinterpret_cast<const unsigned int*>(g),
                                   reinterpret_cast<unsigned int*>(l), 16, 0, 0);
}

// ---------------------------------------------------------------------------
// ws layout (bytes)
//   Apad : [2][132][132][256] bf16  (conv1 out, zero halo of 2) = 17,842,176
//   BT   : [256][6400] bf16  (Wp transposed to [n][k], k=(dh*5+dw)*256+c)
//   Pp   : 2 x [32768][256] bf16 partials (split-K halves) = 33,554,432
// ---------------------------------------------------------------------------
#define APAD_BYTES 17842176
#define BT_OFF     17842176
#define PP_OFF     21118976

// --- K0: fused weight prep (blocks 0..255) + halo zero (blocks 256..515) ---
__global__ __launch_bounds__(256) void prep_halo(const float* __restrict__ Wp,
                                                 unsigned short* __restrict__ BT,
                                                 unsigned short* __restrict__ Apad) {
  __shared__ float w[6400];
  const int bid = blockIdx.x, tid = threadIdx.x;
  if (bid < 256) {
    const float* src = Wp + bid * 6400;
    for (int i = tid; i < 6400; i += 256) w[i] = src[i];
    __syncthreads();
    for (int k = tid; k < 6400; k += 256) {
      int dhw = k >> 8, c = k & 255;
      BT[bid * 6400 + k] = f2bf(w[c * 25 + dhw]);
    }
  } else {
    // 2 images x 1040 halo pixels x 32 us8-chunks = 66,560 writes
    int idx = (bid - 256) * 256 + tid;
    int chunk = idx & 31;
    int pix = idx >> 5;                 // 0..2079
    int img = pix >= 1040;
    int p = pix - img * 1040;
    int h, w2;
    if (p < 528) {                      // rows {0,1,130,131} full width
      int rs = p / 132;
      h = (rs < 2) ? rs : rs + 128;
      w2 = p - rs * 132;
    } else {                            // rows 2..129, cols {0,1,130,131}
      int q = p - 528;
      h = 2 + (q >> 2);
      int cs = q & 3;
      w2 = (cs < 2) ? cs : cs + 128;
    }
    us8 z = {0, 0, 0, 0, 0, 0, 0, 0};
    *(us8*)(Apad + (size_t)(img * 17424 + h * 132 + w2) * 256 + chunk * 8) = z;
  }
}

// --- K1: conv1 = relu(conv5x5(x, W1)+b1), write padded NHWC bf16 -----------
__global__ __launch_bounds__(256) void conv1_k(const float* __restrict__ x,
                                               const float* __restrict__ W1,
                                               const float* __restrict__ b1,
                                               unsigned short* __restrict__ Apad) {
  int t = threadIdx.x;
  int pxt = blockIdx.x >> 3;                 // 512 pixel tiles of 64
  int cq  = blockIdx.x & 7;                  // 8 channel quads of 32
  int px  = (pxt << 6) + (t & 63);           // same (b,h) across the tile
  int cg  = __builtin_amdgcn_readfirstlane(t >> 6);   // wave-uniform
  int co0 = (cq << 5) + (cg << 3);           // 8 channels per thread
  int b = px >> 14, hw = px & 16383;
  int h = hw >> 7, w = hw & 127;

  float patch[25];
#pragma unroll
  for (int dh = 0; dh < 5; ++dh)
#pragma unroll
    for (int dw = 0; dw < 5; ++dw) {
      int hh = h + dh - 2, ww = w + dw - 2;
      bool ok = (hh >= 0) & (hh < 128) & (ww >= 0) & (ww < 128);
      patch[dh * 5 + dw] = ok ? x[(b << 14) + hh * 128 + ww] : 0.f;
    }
  us8 o;
#pragma unroll
  for (int c = 0; c < 8; ++c) {
    float acc = b1[co0 + c];
#pragma unroll
    for (int i = 0; i < 25; ++i) acc += patch[i] * W1[(co0 + c) * 25 + i];
    o[c] = f2bf(fmaxf(acc, 0.f));
  }
  *(us8*)(Apad + (size_t)((b * 132 + h + 2) * 132 + (w + 2)) * 256 + co0) = o;
}

// --- K2: implicit-GEMM conv, 256x256 tile, 8 waves -------------------------
// A (im2col pixels) staged in LDS (ring of 4 BK=32 slots, 16 KB each,
// conflict-free swizzle pair). B (weights, 3.3 MB, L2-resident) read
// DIRECT global->VGPR per fragment: halves LDS read traffic -> MFMA-bound.
// Per unit: 1 VMC(8), 2 barriers, 8 ds_read_b128, 4 B-loads, 2 gld16, 32 MFMA.
#define STAGE_A(slot, ku) do { int dhw_=(ku)>>3, dh_=dhw_/5, dw_=dhw_-dh_*5;   \
    int ao_=((dh_*132+dw_)<<8)+(((ku)&7)<<5);                                  \
    gld16(Aap+abase0+ao_, &As[slot][sA]);                                      \
    gld16(Aap+abase1+ao_, &As[slot][sA+4096]); } while(0)
#define BLOAD(p, u) do { const int kp_ = (t0+(u))<<5;                          \
    bf[p][0] = *(const bf16x8*)(BT + bbF + kp_);                               \
    bf[p][1] = *(const bf16x8*)(BT + bbF + 102400 + kp_);                      \
    bf[p][2] = *(const bf16x8*)(BT + bbF + 204800 + kp_);                      \
    bf[p][3] = *(const bf16x8*)(BT + bbF + 307200 + kp_); } while(0)
#define READ_LO(slot) do { _Pragma("unroll") for (int s_ = 0; s_ < 4; ++s_)    \
    aF[s_] = *(const bf16x8*)(&As[slot][areadbase + s_*512]); } while(0)
#define READ_HI(slot) do { _Pragma("unroll") for (int s_ = 0; s_ < 4; ++s_)    \
    aF[4+s_] = *(const bf16x8*)(&As[slot][areadbase + (4+s_)*512]); } while(0)
#define MF_LO(p) do { _Pragma("unroll") for (int s_ = 0; s_ < 4; ++s_)         \
  _Pragma("unroll") for (int j_ = 0; j_ < 4; ++j_)                             \
    acc[s_][j_] = __builtin_amdgcn_mfma_f32_16x16x32_bf16(                     \
        aF[s_], bf[p][j_], acc[s_][j_], 0, 0, 0); } while(0)
#define MF_HI(p) do { _Pragma("unroll") for (int s_ = 0; s_ < 4; ++s_)         \
  _Pragma("unroll") for (int j_ = 0; j_ < 4; ++j_)                             \
    acc[4+s_][j_] = __builtin_amdgcn_mfma_f32_16x16x32_bf16(                   \
        aF[4+s_], bf[p][j_], acc[4+s_][j_], 0, 0, 0); } while(0)
#define BAR() __builtin_amdgcn_s_barrier()
#define VMC(n) asm volatile("s_waitcnt vmcnt(" #n ")" ::: "memory")
#define SP(n) __builtin_amdgcn_s_setprio(n)

__global__ __launch_bounds__(512, 2) void caps_conv2(
    const unsigned short* __restrict__ Aap,  // Apad NHWC bf16
    const unsigned short* __restrict__ BT,   // [256][6400] bf16
    unsigned short* __restrict__ Pp)         // 2 x [32768][256] bf16 partials
{
  __shared__ __attribute__((aligned(16))) unsigned short As[4][8192];

  const int tid = threadIdx.x;
  const int bid = blockIdx.x;          // 256 blocks
  // bijective XCD-chunked swizzle: per-XCD window L2-resident
  const int lid = (bid & 7) * 32 + (bid >> 3);
  const int kid = lid & 1;
  const int m0 = (lid >> 1) << 8;
  const int t0 = kid * 100;            // 100 k-units of 32 per split-K half
  const int wid = tid >> 6;
  const int l = tid & 63;

  // --- A staging addresses (per-thread, source-preswizzled) ---
  const int swz = (l & 3) ^ ((l >> 3) & 3);   // matches read part q^((row>>1)&3)
  int abase0, abase1;
  {
    int ra = wid * 16 + (l >> 2);               // 0..127
    int m = m0 + ra;
    int b = m >> 14, hw = m & 16383, h = hw >> 7, w = hw & 127;
    abase0 = ((b * 132 + h) * 132 + w) * 256 + swz * 8;
    m = m0 + ra + 128;
    b = m >> 14; hw = m & 16383; h = hw >> 7; w = hw & 127;
    abase1 = ((b * 132 + h) * 132 + w) * 256 + swz * 8;
  }
  const int sA = wid * 512;            // LDS stage base (ushorts)

  // --- fragment addresses ---
  const int rl = l & 15, q = l >> 4;
  const int wm = wid >> 2, wn = wid & 3;       // 2x4 wave grid, tile 128x64
  const int areadbase = (wm * 128 + rl) * 32 + ((q ^ ((rl >> 1) & 3)) << 3);
  const int bbF = (wn * 64 + rl) * 6400 + q * 8;   // B direct-global lane base

  f32x4 acc[8][4] = {};
  bf16x8 aF[8], bf[2][4];

  // --- prologue: stage A(0..2), load B(0); drain A(0); read its frags ---
  STAGE_A(0, t0 + 0); STAGE_A(1, t0 + 1); STAGE_A(2, t0 + 2);
  BLOAD(0, 0);
  VMC(8); BAR();
  READ_LO(0); READ_HI(0);

  // --- main loop: units 0..95 (48 iters x 2 units) ---
  for (int it = 0; it < 48; ++it) {
    const int u = it * 2;
    // unit u (par 0)
    BLOAD(1, u + 1);
    STAGE_A((u + 3) & 3, t0 + u + 3);
    VMC(8); BAR();
    SP(1); MF_LO(0); SP(0);
    READ_LO((u + 1) & 3);
    SP(1); MF_HI(0); SP(0);
    READ_HI((u + 1) & 3);
    BAR();
    // unit u+1 (par 1)
    BLOAD(0, u + 2);
    STAGE_A((u + 4) & 3, t0 + u + 4);
    VMC(8); BAR();
    SP(1); MF_LO(1); SP(0);
    READ_LO((u + 2) & 3);
    SP(1); MF_HI(1); SP(0);
    READ_HI((u + 2) & 3);
    BAR();
  }

  // --- tail: units 96..99 (drain ladder 8/6/8) ---
  // u=96 (par 0): last stage (unit 99 -> slot 3)
  BLOAD(1, 97);
  STAGE_A(3, t0 + 99);
  VMC(8); BAR();
  SP(1); MF_LO(0); SP(0);
  READ_LO(1);
  SP(1); MF_HI(0); SP(0);
  READ_HI(1);
  BAR();
  // u=97 (par 1)
  BLOAD(0, 98);
  VMC(6); BAR();
  SP(1); MF_LO(1); SP(0);
  READ_LO(2);
  SP(1); MF_HI(1); SP(0);
  READ_HI(2);
  BAR();
  // u=98 (par 0)
  BLOAD(1, 99);
  VMC(8); BAR();
  SP(1); MF_LO(0); SP(0);
  READ_LO(3);
  SP(1); MF_HI(0); SP(0);
  READ_HI(3);
  BAR();
  // u=99 (par 1): compiler inserts waits for B(99) regs
  MF_LO(1);
  MF_HI(1);

  // --- epilogue: raw bf16 partial store (squash + bias in tail kernel) ---
  unsigned short* P = Pp + kid * 8388608;
#pragma unroll
  for (int s = 0; s < 8; ++s) {
#pragma unroll
    for (int j = 0; j < 4; ++j) {
      int col = wn * 64 + j * 16 + rl;
      int mrow = m0 + wm * 128 + s * 16 + (q << 2);
#pragma unroll
      for (int e = 0; e < 4; ++e)
        P[(size_t)(mrow + e) * 256 + col] = f2bf(acc[s][j][e]);
    }
  }
}

// --- K3: merge + squash + seg + recon, 2 threads/pixel, chains broken ------
__global__ __launch_bounds__(256) void tail_k3(
    const unsigned short* __restrict__ Pp, const float* __restrict__ y,
    const float* __restrict__ bp, const float* __restrict__ cbp,
    const float* __restrict__ Ws, const float* __restrict__ bs,
    const float* __restrict__ cbs,
    const float* __restrict__ Wr1, const float* __restrict__ br1,
    const float* __restrict__ Wr2, const float* __restrict__ br2,
    const float* __restrict__ Wr3, const float* __restrict__ br3,
    float* __restrict__ out) {
  __shared__ float ccl[256];
  __shared__ float sbl[16];
  __shared__ float Wsl[128];
  __shared__ float W1l[1024];
  __shared__ float b1l[64];
  __shared__ float W2l[8192];
  __shared__ float b2l[128];
  __shared__ float W3l[128];

  const int tid = threadIdx.x;
  ccl[tid] = bp[tid] * (1.f / 32.f) + cbp[tid];
  if (tid < 16) sbl[tid] = 32.f * bs[tid] + cbs[tid];
  if (tid < 128) { Wsl[tid] = Ws[tid]; b2l[tid] = br2[tid]; W3l[tid] = Wr3[tid]; }
  if (tid < 64) b1l[tid] = br1[tid];
  for (int i = tid; i < 1024; i += 256) W1l[i] = Wr1[i];
  for (int i = tid; i < 8192; i += 256) W2l[i] = Wr2[i];
  __syncthreads();

  const int m = blockIdx.x * 128 + (tid >> 1);   // 256 blocks x 128 pixels
  const int hf = tid & 1;                         // half: splits i/j/k loops

  // merge 16 of 32 primary capsules per half
  const us8* pr0 = (const us8*)(Pp + (size_t)m * 256) + hf * 16;
  const us8* pr1 = (const us8*)(Pp + 8388608 + (size_t)m * 256) + hf * 16;
  float P8[8] = {0.f, 0.f, 0.f, 0.f, 0.f, 0.f, 0.f, 0.f};
#pragma unroll 4
  for (int i = 0; i < 16; ++i) {
    us8 a = pr0[i], b = pr1[i];
    const int ci = (hf * 16 + i) * 8;
    float v[8];
#pragma unroll
    for (int c = 0; c < 8; ++c)
      v[c] = (bf2f(a[c]) + bf2f(b[c])) * (1.f / 32.f) + ccl[ci + c];
    float sqa = v[0]*v[0] + v[1]*v[1] + v[2]*v[2] + v[3]*v[3];
    float sqb = v[4]*v[4] + v[5]*v[5] + v[6]*v[6] + v[7]*v[7];
    float sq = sqa + sqb;
    float scale = sq / ((1.f + sq) * sqrtf(sq + 1e-9f));
#pragma unroll
    for (int c = 0; c < 8; ++c) P8[c] += v[c] * scale;
  }
#pragma unroll
  for (int c = 0; c < 8; ++c) P8[c] += __shfl_xor(P8[c], 1);

  // seg preact + squash + length (both halves duplicate: cheap)
  float pre[16];
  float sqx = 0.f, sqy = 0.f;
#pragma unroll
  for (int a = 0; a < 16; ++a) {
    float s0 = P8[0]*Wsl[a*8+0] + P8[1]*Wsl[a*8+1] + P8[2]*Wsl[a*8+2] + P8[3]*Wsl[a*8+3];
    float s1 = P8[4]*Wsl[a*8+4] + P8[5]*Wsl[a*8+5] + P8[6]*Wsl[a*8+6] + P8[7]*Wsl[a*8+7];
    float s = sbl[a] + s0 + s1;
    pre[a] = s;
    if (a & 1) sqy += s * s; else sqx += s * s;
  }
  float sq2 = sqx + sqy;
  float sc2 = sq2 / ((1.f + sq2) * sqrtf(sq2 + 1e-9f));
  if (hf == 0) out[m] = sqrtf(sq2 * sc2 * sc2 + 1e-9f);

  const float f = sc2 * y[m];
  // r1: each half computes 32 of 64 (j = hf*32 + jj)
  float r1o[32];
#pragma unroll
  for (int jj = 0; jj < 32; ++jj) {
    const float* wr = W1l + (hf * 32 + jj) * 16;
    float s0 = 0.f, s1 = 0.f;
#pragma unroll
    for (int a = 0; a < 8; ++a) { s0 += pre[a] * f * wr[a]; s1 += pre[a+8] * f * wr[a+8]; }
    r1o[jj] = fmaxf(b1l[hf * 32 + jj] + s0 + s1, 0.f);
  }
  // exchange: lo = r1[j<32], hi = r1[j>=32] for BOTH halves (static indexing)
  float lo[32], hi[32];
#pragma unroll
  for (int jj = 0; jj < 32; ++jj) {
    float tmp = __shfl_xor(r1o[jj], 1);
    lo[jj] = hf ? tmp : r1o[jj];
    hi[jj] = hf ? r1o[jj] : tmp;
  }
  // recon: each half does 64 of 128 k's, 4 accumulators
  float a0 = 0.f, a1 = 0.f, a2 = 0.f, a3 = 0.f;
#pragma unroll 4
  for (int kk = 0; kk < 64; ++kk) {
    const int k = hf * 64 + kk;
    const float* w = W2l + k * 64;
    float s0 = 0.f, s1 = 0.f, s2 = 0.f, s3 = 0.f;
#pragma unroll
    for (int j = 0; j < 8; ++j) {
      s0 += lo[j] * w[j];        s1 += lo[j + 8] * w[j + 8];
      s2 += lo[j + 16] * w[j + 16]; s3 += lo[j + 24] * w[j + 24];
    }
#pragma unroll
    for (int j = 0; j < 8; ++j) {
      s0 += hi[j] * w[32 + j];        s1 += hi[j + 8] * w[40 + j];
      s2 += hi[j + 16] * w[48 + j];   s3 += hi[j + 24] * w[56 + j];
    }
    float s = b2l[k] + (s0 + s1) + (s2 + s3);
    float t = fmaxf(s, 0.f) * W3l[k];
    switch (kk & 3) { case 0: a0 += t; break; case 1: a1 += t; break;
                      case 2: a2 += t; break; default: a3 += t; }
  }
  float own = (a0 + a1) + (a2 + a3);
  float acc2 = br3[0] + own + __shfl_xor(own, 1);
  if (hf == 0) out[32768 + m] = 1.f / (1.f + expf(-acc2));
}

// ---------------------------------------------------------------------------
extern "C" void kernel_launch(void* const* d_in, const int* in_sizes, int n_in,
                              void* d_out, int out_size, void* d_ws, size_t ws_size,
                              hipStream_t stream) {
  const float* x   = (const float*)d_in[0];
  const float* y   = (const float*)d_in[1];
  const float* W1  = (const float*)d_in[2];
  const float* b1  = (const float*)d_in[3];
  const float* Wp  = (const float*)d_in[4];
  const float* bp  = (const float*)d_in[5];
  const float* cbp = (const float*)d_in[6];
  const float* Ws  = (const float*)d_in[7];
  const float* bs  = (const float*)d_in[8];
  const float* cbs = (const float*)d_in[9];
  const float* Wr1 = (const float*)d_in[10];
  const float* br1 = (const float*)d_in[11];
  const float* Wr2 = (const float*)d_in[12];
  const float* br2 = (const float*)d_in[13];
  const float* Wr3 = (const float*)d_in[14];
  const float* br3 = (const float*)d_in[15];
  float* out = (float*)d_out;

  char* ws = (char*)d_ws;
  unsigned short* Apad = (unsigned short*)ws;
  unsigned short* BT   = (unsigned short*)(ws + BT_OFF);
  unsigned short* Pp   = (unsigned short*)(ws + PP_OFF);

  hipLaunchKernelGGL(prep_halo, dim3(516), dim3(256), 0, stream, Wp, BT, Apad);
  hipLaunchKernelGGL(conv1_k, dim3(4096), dim3(256), 0, stream, x, W1, b1, Apad);
  hipLaunchKernelGGL(caps_conv2, dim3(256), dim3(512), 0, stream, Apad, BT, Pp);
  hipLaunchKernelGGL(tail_k3, dim3(256), dim3(256), 0, stream,
                     Pp, y, bp, cbp, Ws, bs, cbs, Wr1, br1, Wr2, br2, Wr3, br3, out);
}

// Round 8
// 154.751 us; speedup vs baseline: 1.3953x; 1.3953x over previous
//
#include <hip/hip_runtime.h>
#include <hip/hip_bf16.h>

typedef __attribute__((ext_vector_type(8))) unsigned short us8;
typedef __attribute__((ext_vector_type(8))) __bf16 bf16x8;
typedef __attribute__((ext_vector_type(4))) float f32x4;

__device__ __forceinline__ unsigned short f2bf(float f) {
  unsigned int u = __float_as_uint(f);
  u += 0x7FFFu + ((u >> 16) & 1u);   // round-to-nearest-even
  return (unsigned short)(u >> 16);
}
__device__ __forceinline__ float bf2f(unsigned short u) {
  return __uint_as_float(((unsigned int)u) << 16);
}

// direct global->LDS DMA, 16B per lane (dest = wave-uniform base + lane*16)
__device__ __forceinline__ void gld16(const unsigned short* g, unsigned short* l) {
  __builtin_amdgcn_global_load_lds(reinterpret_cast<const unsigned int*>(g),
                                   reinterpret_cast<unsigned int*>(l), 16, 0, 0);
}

// ---------------------------------------------------------------------------
// ws layout (bytes)
//   Apad : [2][132][132][256] bf16  (conv1 out, zero halo of 2) = 17,842,176
//   BT   : [256][6400] bf16  (Wp transposed to [n][k], k=(dh*5+dw)*256+c)
//   Pp   : 2 x [32768][256] bf16 partials (split-K halves) = 33,554,432
// ---------------------------------------------------------------------------
#define APAD_BYTES 17842176
#define BT_OFF     17842176
#define PP_OFF     21118976

// --- K0: fused weight prep (blocks 0..255) + halo zero (blocks 256..515) ---
__global__ __launch_bounds__(256) void prep_halo(const float* __restrict__ Wp,
                                                 unsigned short* __restrict__ BT,
                                                 unsigned short* __restrict__ Apad) {
  __shared__ float w[6400];
  const int bid = blockIdx.x, tid = threadIdx.x;
  if (bid < 256) {
    const float* src = Wp + bid * 6400;
    for (int i = tid; i < 6400; i += 256) w[i] = src[i];
    __syncthreads();
    for (int k = tid; k < 6400; k += 256) {
      int dhw = k >> 8, c = k & 255;
      BT[bid * 6400 + k] = f2bf(w[c * 25 + dhw]);
    }
  } else {
    // 2 images x 1040 halo pixels x 32 us8-chunks = 66,560 writes
    int idx = (bid - 256) * 256 + tid;
    int chunk = idx & 31;
    int pix = idx >> 5;                 // 0..2079
    int img = pix >= 1040;
    int p = pix - img * 1040;
    int h, w2;
    if (p < 528) {                      // rows {0,1,130,131} full width
      int rs = p / 132;
      h = (rs < 2) ? rs : rs + 128;
      w2 = p - rs * 132;
    } else {                            // rows 2..129, cols {0,1,130,131}
      int q = p - 528;
      h = 2 + (q >> 2);
      int cs = q & 3;
      w2 = (cs < 2) ? cs : cs + 128;
    }
    us8 z = {0, 0, 0, 0, 0, 0, 0, 0};
    *(us8*)(Apad + (size_t)(img * 17424 + h * 132 + w2) * 256 + chunk * 8) = z;
  }
}

// --- K1: conv1 = relu(conv5x5(x, W1)+b1), write padded NHWC bf16 -----------
__global__ __launch_bounds__(256) void conv1_k(const float* __restrict__ x,
                                               const float* __restrict__ W1,
                                               const float* __restrict__ b1,
                                               unsigned short* __restrict__ Apad) {
  int t = threadIdx.x;
  int pxt = blockIdx.x >> 3;                 // 512 pixel tiles of 64
  int cq  = blockIdx.x & 7;                  // 8 channel quads of 32
  int px  = (pxt << 6) + (t & 63);           // same (b,h) across the tile
  int cg  = __builtin_amdgcn_readfirstlane(t >> 6);   // wave-uniform
  int co0 = (cq << 5) + (cg << 3);           // 8 channels per thread
  int b = px >> 14, hw = px & 16383;
  int h = hw >> 7, w = hw & 127;

  float patch[25];
#pragma unroll
  for (int dh = 0; dh < 5; ++dh)
#pragma unroll
    for (int dw = 0; dw < 5; ++dw) {
      int hh = h + dh - 2, ww = w + dw - 2;
      bool ok = (hh >= 0) & (hh < 128) & (ww >= 0) & (ww < 128);
      patch[dh * 5 + dw] = ok ? x[(b << 14) + hh * 128 + ww] : 0.f;
    }
  us8 o;
#pragma unroll
  for (int c = 0; c < 8; ++c) {
    float acc = b1[co0 + c];
#pragma unroll
    for (int i = 0; i < 25; ++i) acc += patch[i] * W1[(co0 + c) * 25 + i];
    o[c] = f2bf(fmaxf(acc, 0.f));
  }
  *(us8*)(Apad + (size_t)((b * 132 + h + 2) * 132 + (w + 2)) * 256 + co0) = o;
}

// --- K2: implicit-GEMM conv, 256x256 tile, 8 waves ------------------------
// Reg-double-buffered pipeline, ONE barrier + ONE counted VMC(4) per k-unit:
//   body u: READ(slot u+1 -> other reg set) | STAGE(u+3) | MFMA(current set)
//           VMC(4); sched_barrier(0); s_barrier
// MFMA consumes LAST unit's registers -> no lgkm dependency in the cluster;
// ds_reads + gld16 service under the MFMA cluster. sched_barrier pins the
// MFMA cluster (and its lgkm drains) pre-barrier => slot overwrite (stage at
// body u+2 targets slot u+1) is safely one barrier after the reads drain.
// VMC(4) invariant: each body leaves only its own 4 loads in flight, so
// slot(u+1) (staged at body u-2, drained at body u-1) is landed at READ.
#define STAGE(slot, ku) do { int dhw_=(ku)>>3, dh_=dhw_/5, dw_=dhw_-dh_*5;     \
    int ao_=((dh_*132+dw_)<<8)+(((ku)&7)<<5);                                  \
    int kp_=(ku)<<5;                                                           \
    gld16(Aap+abase0+ao_, &As[slot][sA]);                                      \
    gld16(Aap+abase1+ao_, &As[slot][sA+4096]);                                 \
    gld16(BT+bbase0+kp_, &Bs[slot][sA]);                                       \
    gld16(BT+bbase1+kp_, &Bs[slot][sA+4096]); } while(0)
#define READ_SET(AST, BST, slot) do {                                          \
  _Pragma("unroll") for (int s_ = 0; s_ < 8; ++s_)                             \
    AST[s_] = *(const bf16x8*)(&As[slot][areadbase + s_*512]);                 \
  _Pragma("unroll") for (int j_ = 0; j_ < 4; ++j_)                             \
    BST[j_] = *(const bf16x8*)(&Bs[slot][breadbase + j_*512]); } while(0)
#define MFMA_SET(AST, BST) do {                                                \
  _Pragma("unroll") for (int s_ = 0; s_ < 8; ++s_)                             \
  _Pragma("unroll") for (int j_ = 0; j_ < 4; ++j_)                             \
    acc[s_][j_] = __builtin_amdgcn_mfma_f32_16x16x32_bf16(                     \
        AST[s_], BST[j_], acc[s_][j_], 0, 0, 0); } while(0)
#define BAR() __builtin_amdgcn_s_barrier()
#define VMC(n) asm volatile("s_waitcnt vmcnt(" #n ")" ::: "memory")
#define SB0() __builtin_amdgcn_sched_barrier(0)
#define SP(n) __builtin_amdgcn_s_setprio(n)

__global__ __launch_bounds__(512, 1) void caps_conv2(
    const unsigned short* __restrict__ Aap,  // Apad NHWC bf16
    const unsigned short* __restrict__ BT,   // [256][6400] bf16
    unsigned short* __restrict__ Pp)         // 2 x [32768][256] bf16 partials
{
  __shared__ __attribute__((aligned(16))) unsigned short As[4][8192];
  __shared__ __attribute__((aligned(16))) unsigned short Bs[4][8192];

  const int tid = threadIdx.x;
  const int bid = blockIdx.x;          // 256 blocks
  // bijective XCD-chunked swizzle: per-XCD window L2-resident
  const int lid = (bid & 7) * 32 + (bid >> 3);
  const int kid = lid & 1;
  const int m0 = (lid >> 1) << 8;
  const int t0 = kid * 100;            // 100 k-units of 32 per split-K half
  const int wid = tid >> 6;
  const int l = tid & 63;

  // --- staging addresses (per-thread, source-preswizzled) ---
  const int swz = (l & 3) ^ ((l >> 3) & 3);   // matches read part q^((row>>1)&3)
  int abase0, abase1, bbase0, bbase1;
  {
    int ra = wid * 16 + (l >> 2);               // 0..127
    int m = m0 + ra;
    int b = m >> 14, hw = m & 16383, h = hw >> 7, w = hw & 127;
    abase0 = ((b * 132 + h) * 132 + w) * 256 + swz * 8;
    m = m0 + ra + 128;
    b = m >> 14; hw = m & 16383; h = hw >> 7; w = hw & 127;
    abase1 = ((b * 132 + h) * 132 + w) * 256 + swz * 8;
    bbase0 = ra * 6400 + swz * 8;
    bbase1 = (ra + 128) * 6400 + swz * 8;
  }
  const int sA = wid * 512;            // LDS stage base (ushorts)

  // --- fragment-read addresses ---
  const int rl = l & 15, q = l >> 4;
  const int wm = wid >> 2, wn = wid & 3;       // 2x4 wave grid, tile 128x64
  const int areadbase = (wm * 128 + rl) * 32 + ((q ^ ((rl >> 1) & 3)) << 3);
  const int breadbase = (wn * 64 + rl) * 32 + ((q ^ ((rl >> 1) & 3)) << 3);

  f32x4 acc[8][4] = {};
  bf16x8 aR0[8], bR0[4], aR1[8], bR1[4];

  // --- prologue: stage units 0,1,2; drain slots 0&1; preload slot 0 ---
  STAGE(0, t0 + 0); STAGE(1, t0 + 1); STAGE(2, t0 + 2);
  VMC(4); BAR();
  READ_SET(aR0, bR0, 0);

  // --- main loop: bodies 0..95 (48 iters x 2) ---
  for (int it = 0; it < 48; ++it) {
    const int u = it * 2;
    // body u (even): cur=set0, next into set1
    READ_SET(aR1, bR1, (u + 1) & 3);
    STAGE((u + 3) & 3, t0 + u + 3);
    SP(1); MFMA_SET(aR0, bR0); SP(0);
    VMC(4); SB0(); BAR();
    // body u+1 (odd): cur=set1, next into set0
    READ_SET(aR0, bR0, (u + 2) & 3);
    STAGE((u + 4) & 3, t0 + u + 4);
    SP(1); MFMA_SET(aR1, bR1); SP(0);
    VMC(4); SB0(); BAR();
  }
  // body 96: last stage (unit 99 -> slot 3)
  READ_SET(aR1, bR1, 1);
  STAGE(3, t0 + 99);
  SP(1); MFMA_SET(aR0, bR0); SP(0);
  VMC(4); SB0(); BAR();
  // body 97: no stage; drain all so slot 3 (unit 99) is landed
  READ_SET(aR0, bR0, 2);
  SP(1); MFMA_SET(aR1, bR1); SP(0);
  VMC(0); SB0(); BAR();
  // body 98
  READ_SET(aR1, bR1, 3);
  SP(1); MFMA_SET(aR0, bR0); SP(0);
  // body 99
  MFMA_SET(aR1, bR1);

  // --- epilogue: raw bf16 partial store (squash + bias in tail kernel) ---
  unsigned short* P = Pp + kid * 8388608;
#pragma unroll
  for (int s = 0; s < 8; ++s) {
#pragma unroll
    for (int j = 0; j < 4; ++j) {
      int col = wn * 64 + j * 16 + rl;
      int mrow = m0 + wm * 128 + s * 16 + (q << 2);
#pragma unroll
      for (int e = 0; e < 4; ++e)
        P[(size_t)(mrow + e) * 256 + col] = f2bf(acc[s][j][e]);
    }
  }
}

// --- K3: merge + squash + seg + recon, 2 threads/pixel, chains broken ------
__global__ __launch_bounds__(256) void tail_k3(
    const unsigned short* __restrict__ Pp, const float* __restrict__ y,
    const float* __restrict__ bp, const float* __restrict__ cbp,
    const float* __restrict__ Ws, const float* __restrict__ bs,
    const float* __restrict__ cbs,
    const float* __restrict__ Wr1, const float* __restrict__ br1,
    const float* __restrict__ Wr2, const float* __restrict__ br2,
    const float* __restrict__ Wr3, const float* __restrict__ br3,
    float* __restrict__ out) {
  __shared__ float ccl[256];
  __shared__ float sbl[16];
  __shared__ float Wsl[128];
  __shared__ float W1l[1024];
  __shared__ float b1l[64];
  __shared__ float W2l[8192];
  __shared__ float b2l[128];
  __shared__ float W3l[128];

  const int tid = threadIdx.x;
  ccl[tid] = bp[tid] * (1.f / 32.f) + cbp[tid];
  if (tid < 16) sbl[tid] = 32.f * bs[tid] + cbs[tid];
  if (tid < 128) { Wsl[tid] = Ws[tid]; b2l[tid] = br2[tid]; W3l[tid] = Wr3[tid]; }
  if (tid < 64) b1l[tid] = br1[tid];
  for (int i = tid; i < 1024; i += 256) W1l[i] = Wr1[i];
  for (int i = tid; i < 8192; i += 256) W2l[i] = Wr2[i];
  __syncthreads();

  const int m = blockIdx.x * 128 + (tid >> 1);   // 256 blocks x 128 pixels
  const int hf = tid & 1;                         // half: splits i/j/k loops

  // merge 16 of 32 primary capsules per half
  const us8* pr0 = (const us8*)(Pp + (size_t)m * 256) + hf * 16;
  const us8* pr1 = (const us8*)(Pp + 8388608 + (size_t)m * 256) + hf * 16;
  float P8[8] = {0.f, 0.f, 0.f, 0.f, 0.f, 0.f, 0.f, 0.f};
#pragma unroll 4
  for (int i = 0; i < 16; ++i) {
    us8 a = pr0[i], b = pr1[i];
    const int ci = (hf * 16 + i) * 8;
    float v[8];
#pragma unroll
    for (int c = 0; c < 8; ++c)
      v[c] = (bf2f(a[c]) + bf2f(b[c])) * (1.f / 32.f) + ccl[ci + c];
    float sqa = v[0]*v[0] + v[1]*v[1] + v[2]*v[2] + v[3]*v[3];
    float sqb = v[4]*v[4] + v[5]*v[5] + v[6]*v[6] + v[7]*v[7];
    float sq = sqa + sqb;
    float scale = sq / ((1.f + sq) * sqrtf(sq + 1e-9f));
#pragma unroll
    for (int c = 0; c < 8; ++c) P8[c] += v[c] * scale;
  }
#pragma unroll
  for (int c = 0; c < 8; ++c) P8[c] += __shfl_xor(P8[c], 1);

  // seg preact + squash + length (both halves duplicate: cheap)
  float pre[16];
  float sqx = 0.f, sqy = 0.f;
#pragma unroll
  for (int a = 0; a < 16; ++a) {
    float s0 = P8[0]*Wsl[a*8+0] + P8[1]*Wsl[a*8+1] + P8[2]*Wsl[a*8+2] + P8[3]*Wsl[a*8+3];
    float s1 = P8[4]*Wsl[a*8+4] + P8[5]*Wsl[a*8+5] + P8[6]*Wsl[a*8+6] + P8[7]*Wsl[a*8+7];
    float s = sbl[a] + s0 + s1;
    pre[a] = s;
    if (a & 1) sqy += s * s; else sqx += s * s;
  }
  float sq2 = sqx + sqy;
  float sc2 = sq2 / ((1.f + sq2) * sqrtf(sq2 + 1e-9f));
  if (hf == 0) out[m] = sqrtf(sq2 * sc2 * sc2 + 1e-9f);

  const float f = sc2 * y[m];
  // r1: each half computes 32 of 64 (j = hf*32 + jj)
  float r1o[32];
#pragma unroll
  for (int jj = 0; jj < 32; ++jj) {
    const float* wr = W1l + (hf * 32 + jj) * 16;
    float s0 = 0.f, s1 = 0.f;
#pragma unroll
    for (int a = 0; a < 8; ++a) { s0 += pre[a] * f * wr[a]; s1 += pre[a+8] * f * wr[a+8]; }
    r1o[jj] = fmaxf(b1l[hf * 32 + jj] + s0 + s1, 0.f);
  }
  // exchange: lo = r1[j<32], hi = r1[j>=32] for BOTH halves (static indexing)
  float lo[32], hi[32];
#pragma unroll
  for (int jj = 0; jj < 32; ++jj) {
    float tmp = __shfl_xor(r1o[jj], 1);
    lo[jj] = hf ? tmp : r1o[jj];
    hi[jj] = hf ? r1o[jj] : tmp;
  }
  // recon: each half does 64 of 128 k's, 4 accumulators
  float a0 = 0.f, a1 = 0.f, a2 = 0.f, a3 = 0.f;
#pragma unroll 4
  for (int kk = 0; kk < 64; ++kk) {
    const int k = hf * 64 + kk;
    const float* w = W2l + k * 64;
    float s0 = 0.f, s1 = 0.f, s2 = 0.f, s3 = 0.f;
#pragma unroll
    for (int j = 0; j < 8; ++j) {
      s0 += lo[j] * w[j];        s1 += lo[j + 8] * w[j + 8];
      s2 += lo[j + 16] * w[j + 16]; s3 += lo[j + 24] * w[j + 24];
    }
#pragma unroll
    for (int j = 0; j < 8; ++j) {
      s0 += hi[j] * w[32 + j];        s1 += hi[j + 8] * w[40 + j];
      s2 += hi[j + 16] * w[48 + j];   s3 += hi[j + 24] * w[56 + j];
    }
    float s = b2l[k] + (s0 + s1) + (s2 + s3);
    float t = fmaxf(s, 0.f) * W3l[k];
    switch (kk & 3) { case 0: a0 += t; break; case 1: a1 += t; break;
                      case 2: a2 += t; break; default: a3 += t; }
  }
  float own = (a0 + a1) + (a2 + a3);
  float acc2 = br3[0] + own + __shfl_xor(own, 1);
  if (hf == 0) out[32768 + m] = 1.f / (1.f + expf(-acc2));
}

// ---------------------------------------------------------------------------
extern "C" void kernel_launch(void* const* d_in, const int* in_sizes, int n_in,
                              void* d_out, int out_size, void* d_ws, size_t ws_size,
                              hipStream_t stream) {
  const float* x   = (const float*)d_in[0];
  const float* y   = (const float*)d_in[1];
  const float* W1  = (const float*)d_in[2];
  const float* b1  = (const float*)d_in[3];
  const float* Wp  = (const float*)d_in[4];
  const float* bp  = (const float*)d_in[5];
  const float* cbp = (const float*)d_in[6];
  const float* Ws  = (const float*)d_in[7];
  const float* bs  = (const float*)d_in[8];
  const float* cbs = (const float*)d_in[9];
  const float* Wr1 = (const float*)d_in[10];
  const float* br1 = (const float*)d_in[11];
  const float* Wr2 = (const float*)d_in[12];
  const float* br2 = (const float*)d_in[13];
  const float* Wr3 = (const float*)d_in[14];
  const float* br3 = (const float*)d_in[15];
  float* out = (float*)d_out;

  char* ws = (char*)d_ws;
  unsigned short* Apad = (unsigned short*)ws;
  unsigned short* BT   = (unsigned short*)(ws + BT_OFF);
  unsigned short* Pp   = (unsigned short*)(ws + PP_OFF);

  hipLaunchKernelGGL(prep_halo, dim3(516), dim3(256), 0, stream, Wp, BT, Apad);
  hipLaunchKernelGGL(conv1_k, dim3(4096), dim3(256), 0, stream, x, W1, b1, Apad);
  hipLaunchKernelGGL(caps_conv2, dim3(256), dim3(512), 0, stream, Apad, BT, Pp);
  hipLaunchKernelGGL(tail_k3, dim3(256), dim3(256), 0, stream,
                     Pp, y, bp, cbp, Ws, bs, cbs, Wr1, br1, Wr2, br2, Wr3, br3, out);
}